// Round 10
// baseline (5913.749 us; speedup 1.0000x reference)
//
#include <hip/hip_runtime.h>
#include <hip/hip_bf16.h>
#include <math.h>

#define BB 2
#define SS 25
#define NNODE 5000
#define EE 15000
#define NG 50          /* B*S graphs */
#define ZZ 32
#define FF_DIM 1024
#define NL 4
#define NH 4
#define HD 8
#define E1C 64
#define E2C 128
#define E3C 256
#define CDIM 12
#define LN_EPS 1e-5f

// ---------- edge dtype detector: int64 edges read as int32 pairs have all-zero
// odd (high) words; genuine int32 edges have nonzero odd words (dst) ----------
__global__ void k_edetect(const int* __restrict__ w, int* __restrict__ eflag) {
  __shared__ int nz;
  if (threadIdx.x == 0) nz = 0;
  __syncthreads();
  int cnt = 0;
  for (int i = threadIdx.x; i < 2048; i += 256)
    if (w[2 * i + 1] != 0) cnt++;
  atomicAdd(&nz, cnt);
  __syncthreads();
  if (threadIdx.x == 0) *eflag = (nz < 100) ? 1 : 0;  // 1 => int64 layout
}

__global__ __launch_bounds__(256) void k_ecvt(const int* __restrict__ w,
    int* __restrict__ el32, int n, const int* __restrict__ eflag) {
  int i = blockIdx.x * 256 + threadIdx.x;
  if (i >= n) return;
  el32[i] = (*eflag) ? w[2 * i] : w[i];
}

// ---------------- skeleton embedding: relu(v @ Wemb^T + b) ----------------
__global__ __launch_bounds__(256) void k_emb(const float* __restrict__ v,
    const float* __restrict__ W, const float* __restrict__ b,
    float* __restrict__ X0, int M, int node0) {
  int idx = blockIdx.x * 256 + threadIdx.x;
  if (idx >= M * 64) return;
  int node = idx >> 6, o = idx & 63;
  const float* vp = v + (size_t)(node0 + node) * 3;
  float acc = b[o] + vp[0] * W[o * 3 + 0] + vp[1] * W[o * 3 + 1] + vp[2] * W[o * 3 + 2];
  X0[idx] = acc > 0.f ? acc : 0.f;
}

__global__ void k_zero_int(int* p, int n) {
  int i = blockIdx.x * 256 + threadIdx.x;
  if (i < n) p[i] = 0;
}

__global__ void k_deg(const int* __restrict__ el, int* __restrict__ cnt, int edge0) {
  int e = blockIdx.x * 256 + threadIdx.x;
  int g = blockIdx.y;
  if (e >= EE) return;
  int dst = el[(size_t)(edge0 + g * EE + e) * 2 + 1];
  if ((unsigned)dst >= NNODE) return;  // guard
  atomicAdd(&cnt[g * NNODE + dst], 1);
}

__global__ void k_dinv(const int* __restrict__ cnt, float* __restrict__ dinv, int M) {
  int i = blockIdx.x * 256 + threadIdx.x;
  if (i >= M) return;
  dinv[i] = rsqrtf((float)cnt[i] + 1.0f);
}

// --------------- tiled C[M,N] = (opt leaky)A[M,K] @ W[K,N] ---------------
template <int K, bool LEAKY>
__global__ __launch_bounds__(256) void k_gemm(const float* __restrict__ A,
    const float* __restrict__ W, float* __restrict__ C, int M, int N) {
  __shared__ float As[32][K + 1];
  __shared__ float Ws[K][64];
  int m0 = blockIdx.x * 32, n0 = blockIdx.y * 64;
  int tid = threadIdx.x;
  for (int i = tid; i < K * 64; i += 256) {
    int k = i >> 6, c = i & 63;
    Ws[k][c] = W[k * N + n0 + c];
  }
  for (int i = tid; i < 32 * K; i += 256) {
    int r = i / K, k = i % K;
    float a = 0.f;
    int row = m0 + r;
    if (row < M) {
      a = A[(size_t)row * K + k];
      if (LEAKY) a = a > 0.f ? a : 0.15f * a;
    }
    As[r][k] = a;
  }
  __syncthreads();
  int tx = tid & 15, ty = tid >> 4;
  float acc[2][4] = {{0.f, 0.f, 0.f, 0.f}, {0.f, 0.f, 0.f, 0.f}};
#pragma unroll
  for (int k = 0; k < K; ++k) {
    float a0 = As[ty][k], a1 = As[ty + 16][k];
    float w0 = Ws[k][tx * 4 + 0], w1 = Ws[k][tx * 4 + 1];
    float w2 = Ws[k][tx * 4 + 2], w3 = Ws[k][tx * 4 + 3];
    acc[0][0] += a0 * w0; acc[0][1] += a0 * w1; acc[0][2] += a0 * w2; acc[0][3] += a0 * w3;
    acc[1][0] += a1 * w0; acc[1][1] += a1 * w1; acc[1][2] += a1 * w2; acc[1][3] += a1 * w3;
  }
#pragma unroll
  for (int i = 0; i < 2; ++i) {
    int row = m0 + ty + i * 16;
    if (row < M) {
      float* cp = C + (size_t)row * N + n0 + tx * 4;
      cp[0] = acc[i][0]; cp[1] = acc[i][1]; cp[2] = acc[i][2]; cp[3] = acc[i][3];
    }
  }
}

// AGG = H*dinv^2 + bias (self-loop term, zero-inits accumulator)
template <int C>
__global__ __launch_bounds__(256) void k_agginit(const float* __restrict__ H,
    const float* __restrict__ dinv, const float* __restrict__ bias,
    float* __restrict__ AGG, int M) {
  int idx = blockIdx.x * 256 + threadIdx.x;
  if (idx >= M * C) return;
  int node = idx / C, c = idx % C;
  float di = dinv[node];
  AGG[idx] = H[idx] * di * di + bias[c];
}

// AGG[dst] += H[src]*coef  (atomic scatter over edges)
template <int C, int EPB>
__global__ __launch_bounds__(256) void k_scatter(const int* __restrict__ el,
    const float* __restrict__ H, const float* __restrict__ dinv,
    float* __restrict__ AGG, int edge0) {
  int g = blockIdx.y;
  int e = blockIdx.x * EPB + threadIdx.x / C;
  int c = threadIdx.x % C;
  const int* ep = el + (size_t)(edge0 + g * EE + e) * 2;
  int src = ep[0], dst = ep[1];
  if ((unsigned)src >= NNODE || (unsigned)dst >= NNODE) return;  // guard
  float coef = dinv[g * NNODE + src] * dinv[g * NNODE + dst];
  atomicAdd(&AGG[((size_t)g * NNODE + dst) * C + c],
            H[((size_t)g * NNODE + src) * C + c] * coef);
}

// ---- max-pool via order-preserving uint atomics ----
__device__ __forceinline__ unsigned int f2u_mono(float f) {
  unsigned int u = __float_as_uint(f);
  return (u & 0x80000000u) ? ~u : (u | 0x80000000u);
}
__device__ __forceinline__ float u2f_mono(unsigned int m) {
  unsigned int u = (m & 0x80000000u) ? (m & 0x7FFFFFFFu) : ~m;
  return __uint_as_float(u);
}

__global__ void k_pool_init(unsigned int* pp, int n) {
  int i = blockIdx.x * 256 + threadIdx.x;
  if (i < n) pp[i] = 0u;
}

#define PSLICE 20
__global__ __launch_bounds__(256) void k_pool_atomic(const float* __restrict__ AGG2,
    unsigned int* __restrict__ pp, int g0) {
  int gl = blockIdx.x, sl = blockIdx.y, c = threadIdx.x;
  const int per = NNODE / PSLICE;  // 250
  float m = -1e30f;
  const float* p = AGG2 + (size_t)gl * NNODE * E3C + (size_t)sl * per * E3C + c;
  for (int n = 0; n < per; ++n) m = fmaxf(m, p[(size_t)n * E3C]);
  atomicMax(&pp[(g0 + gl) * E3C + c], f2u_mono(m));
}

__global__ void k_pool_final(const unsigned int* __restrict__ pp,
    float* __restrict__ pooled) {
  int i = blockIdx.x * 256 + threadIdx.x;
  if (i >= NG * E3C) return;
  float m = u2f_mono(pp[i]);
  pooled[i] = m > 0.f ? m : 0.15f * m;  // leaky after max (monotone)
}

__global__ __launch_bounds__(64) void k_fc(const float* __restrict__ pooled,
    const float* __restrict__ con, const float* __restrict__ W,
    const float* __restrict__ bias, float* __restrict__ xfc) {
  int g = blockIdx.x;
  int z = threadIdx.x;
  if (z >= ZZ) return;
  int b = g / SS;
  float acc = bias[z];
  const float* pr = pooled + g * E3C;
  for (int i = 0; i < E3C; ++i) acc += pr[i] * W[i * ZZ + z];
  for (int i = 0; i < CDIM; ++i) acc += con[b * CDIM + i] * W[(E3C + i) * ZZ + z];
  xfc[g * ZZ + z] = acc > 0.f ? acc : 0.f;
}

// xseq[t,b,:] = {muQ, sigQ, xfc[b,t-2]} + posenc(t)
__global__ __launch_bounds__(64) void k_build(const float* __restrict__ muQ,
    const float* __restrict__ sigQ, const float* __restrict__ xfc,
    float* __restrict__ xA) {
  int t = blockIdx.x;
  int z = threadIdx.x & 31, b = threadIdx.x >> 5;
  float val;
  if (t == 0)      val = muQ[z];
  else if (t == 1) val = sigQ[z];
  else             val = xfc[(b * SS + (t - 2)) * ZZ + z];
  int i = z >> 1;
  float freq = expf(-(float)(2 * i) * (logf(10000.f) / 32.f));
  float ang = (float)t * freq;
  float pe = (z & 1) ? cosf(ang) : sinf(ang);
  xA[(t * BB + b) * ZZ + z] = val + pe;
}

// one encoder layer's attention half: xout = LN1(x + proj(attn(x)))
__global__ __launch_bounds__(512) void k_attn(const float* __restrict__ xin,
    float* __restrict__ xout, const float* __restrict__ Wqkv,
    const float* __restrict__ bqkv, const float* __restrict__ Wo,
    const float* __restrict__ bo, const float* __restrict__ l1s,
    const float* __restrict__ l1b) {
  const int T = SS + 2, TB = T * BB;  // 27, 54
  __shared__ float xs[54 * 32];
  __shared__ float qk[54 * 96];
  __shared__ float os[54 * 32];
  __shared__ float ys[54 * 32];
  int tid = threadIdx.x;
  for (int i = tid; i < TB * ZZ; i += 512) xs[i] = xin[i];
  __syncthreads();
  for (int i = tid; i < TB * 96; i += 512) {
    int tb = i / 96, j = i % 96;
    float acc = bqkv[j];
#pragma unroll
    for (int d = 0; d < ZZ; ++d) acc += xs[tb * ZZ + d] * Wqkv[j * ZZ + d];
    qk[i] = acc;
  }
  __syncthreads();
  if (tid < BB * NH * T) {
    int t = tid % T;
    int bh = tid / T;
    int h = bh % NH, b = bh / NH;
    float q[HD];
#pragma unroll
    for (int d = 0; d < HD; ++d) q[d] = qk[(t * BB + b) * 96 + h * HD + d];
    float sc[27];
    float mx = -1e30f;
#pragma unroll
    for (int s = 0; s < T; ++s) {
      float a = 0.f;
#pragma unroll
      for (int d = 0; d < HD; ++d) a += q[d] * qk[(s * BB + b) * 96 + 32 + h * HD + d];
      a *= 0.35355339059327373f;  // 1/sqrt(8)
      sc[s] = a;
      mx = fmaxf(mx, a);
    }
    float sum = 0.f;
#pragma unroll
    for (int s = 0; s < T; ++s) { float e = expf(sc[s] - mx); sc[s] = e; sum += e; }
    float inv = 1.f / sum;
    float o[HD];
#pragma unroll
    for (int d = 0; d < HD; ++d) o[d] = 0.f;
#pragma unroll
    for (int s = 0; s < T; ++s) {
      float a = sc[s] * inv;
#pragma unroll
      for (int d = 0; d < HD; ++d) o[d] += a * qk[(s * BB + b) * 96 + 64 + h * HD + d];
    }
#pragma unroll
    for (int d = 0; d < HD; ++d) os[(t * BB + b) * ZZ + h * HD + d] = o[d];
  }
  __syncthreads();
  for (int i = tid; i < TB * ZZ; i += 512) {
    int tb = i / ZZ, j = i % ZZ;
    float acc = bo[j];
#pragma unroll
    for (int d = 0; d < ZZ; ++d) acc += os[tb * ZZ + d] * Wo[j * ZZ + d];
    ys[i] = xs[i] + acc;  // residual
  }
  __syncthreads();
  if (tid < TB) {
    float m = 0.f;
#pragma unroll
    for (int z = 0; z < ZZ; ++z) m += ys[tid * ZZ + z];
    m *= (1.f / ZZ);
    float vv = 0.f;
#pragma unroll
    for (int z = 0; z < ZZ; ++z) { float d = ys[tid * ZZ + z] - m; vv += d * d; }
    float r = rsqrtf(vv * (1.f / ZZ) + LN_EPS);
    for (int z = 0; z < ZZ; ++z)
      xout[tid * ZZ + z] = (ys[tid * ZZ + z] - m) * r * l1s[z] + l1b[z];
  }
}

// one encoder layer's FF half (per token): xout = LN2(x + W2 gelu(W1 x))
__global__ __launch_bounds__(256) void k_ff(const float* __restrict__ xin,
    float* __restrict__ xout, const float* __restrict__ W1,
    const float* __restrict__ b1, const float* __restrict__ W2,
    const float* __restrict__ b2, const float* __restrict__ l2s,
    const float* __restrict__ l2b) {
  int tb = blockIdx.x;
  __shared__ float xt[ZZ];
  __shared__ float h[FF_DIM];
  __shared__ float yo[ZZ];
  __shared__ float stats[2];
  int tid = threadIdx.x;
  if (tid < ZZ) xt[tid] = xin[tb * ZZ + tid];
  __syncthreads();
  for (int f = tid; f < FF_DIM; f += 256) {
    float acc = b1[f];
#pragma unroll
    for (int d = 0; d < ZZ; ++d) acc += xt[d] * W1[f * ZZ + d];
    h[f] = 0.5f * acc * (1.f + erff(acc * 0.70710678118654752f));  // exact gelu
  }
  __syncthreads();
  int wid = tid >> 6, lane = tid & 63;
  for (int o = wid; o < ZZ; o += 4) {
    float p = 0.f;
    for (int f = lane; f < FF_DIM; f += 64) p += h[f] * W2[o * FF_DIM + f];
#pragma unroll
    for (int off = 32; off; off >>= 1) p += __shfl_down(p, off);
    if (lane == 0) yo[o] = p + b2[o];
  }
  __syncthreads();
  if (tid == 0) {
    float m = 0.f;
    for (int z = 0; z < ZZ; ++z) { yo[z] += xt[z]; m += yo[z]; }
    m *= (1.f / ZZ);
    float vv = 0.f;
    for (int z = 0; z < ZZ; ++z) { float d = yo[z] - m; vv += d * d; }
    stats[0] = m;
    stats[1] = rsqrtf(vv * (1.f / ZZ) + LN_EPS);
  }
  __syncthreads();
  if (tid < ZZ)
    xout[tb * ZZ + tid] = (yo[tid] - stats[0]) * stats[1] * l2s[tid] + l2b[tid];
}

// *** output dtype = FLOAT32 (reference returns f32) — the round-9 fix ***
__global__ void k_out(const float* __restrict__ xA, float* __restrict__ out) {
  int i = blockIdx.x * 256 + threadIdx.x;
  if (i >= 1856) return;
  out[i] = (i < 128) ? xA[i] : xA[i - 128];
}

extern "C" void kernel_launch(void* const* d_in, const int* in_sizes, int n_in,
                              void* d_out, int out_size, void* d_ws, size_t ws_size,
                              hipStream_t stream) {
  // dict order (fingerprint-confirmed r9), f32 inputs (confirmed r5)
  const float* v    = (const float*)d_in[0];
  const int*   el   = (const int*)d_in[1];
  const float* con  = (const float*)d_in[2];
  const float* Wemb = (const float*)d_in[3];
  const float* bemb = (const float*)d_in[4];
  const float* Wg1  = (const float*)d_in[5];
  const float* bg1  = (const float*)d_in[6];
  const float* Wg2  = (const float*)d_in[7];
  const float* bg2  = (const float*)d_in[8];
  const float* Wfc  = (const float*)d_in[9];
  const float* bfc  = (const float*)d_in[10];
  const float* muQ  = (const float*)d_in[11];
  const float* sigQ = (const float*)d_in[12];
  const float* Wqkv = (const float*)d_in[13];
  const float* bqkv = (const float*)d_in[14];
  const float* Wo   = (const float*)d_in[15];
  const float* bo   = (const float*)d_in[16];
  const float* l1s  = (const float*)d_in[17];
  const float* l1b  = (const float*)d_in[18];
  const float* l2s  = (const float*)d_in[19];
  const float* l2b  = (const float*)d_in[20];
  const float* W1   = (const float*)d_in[21];
  const float* b1   = (const float*)d_in[22];
  const float* W2   = (const float*)d_in[23];
  const float* b2   = (const float*)d_in[24];

  // ---- workspace layout ----
  char* base = (char*)d_ws;
  int* eflag = (int*)base;
  float* pooled = (float*)(base + 256);    // 50*256
  float* xfc    = pooled + NG * E3C;       // 50*32
  float* xA     = xfc + NG * ZZ;           // 54*32
  float* xB     = xA + 27 * BB * ZZ;       // 54*32
  unsigned int* pp = (unsigned int*)(xB + 27 * BB * ZZ);  // 50*256

  int*  el32 = (int*)(base + (2u << 20));  // 1.5M ints = 6MB  (at +2MB)
  char* cb   = base + (9u << 20);          // chunk region at +9MB

  k_edetect<<<1, 256, 0, stream>>>(el, eflag);
  k_ecvt<<<(NG * EE * 2 + 255) / 256, 256, 0, stream>>>(el, el32, NG * EE * 2, eflag);

  // chunk bytes/node: X0 256 + H1 512 + A1 512 + H2 1024 + A2 1024 + cnt 4 + dinv 4 = 3336
  int Gc = 1;
  const int opts[5] = {50, 25, 10, 5, 1};
  for (int oi = 0; oi < 5; ++oi) {
    size_t need = (size_t)(9u << 20) + (size_t)opts[oi] * NNODE * 3336ull;
    if (need <= ws_size) { Gc = opts[oi]; break; }
  }
  int M = Gc * NNODE;
  float* X0  = (float*)cb;
  float* H1  = X0 + (size_t)M * E1C;
  float* A1  = H1 + (size_t)M * E2C;
  float* H2  = A1 + (size_t)M * E2C;
  float* A2  = H2 + (size_t)M * E3C;
  int*   cnt = (int*)(A2 + (size_t)M * E3C);
  float* dinv = (float*)(cnt + M);

  k_pool_init<<<(NG * E3C + 255) / 256, 256, 0, stream>>>(pp, NG * E3C);
  for (int g0 = 0; g0 < NG; g0 += Gc) {
    int node0 = g0 * NNODE, edge0 = g0 * EE;
    k_emb<<<(M * 64 + 255) / 256, 256, 0, stream>>>(v, Wemb, bemb, X0, M, node0);
    k_zero_int<<<(M + 255) / 256, 256, 0, stream>>>(cnt, M);
    k_deg<<<dim3((EE + 255) / 256, Gc), 256, 0, stream>>>(el32, cnt, edge0);
    k_dinv<<<(M + 255) / 256, 256, 0, stream>>>(cnt, dinv, M);
    k_gemm<E1C, false><<<dim3((M + 31) / 32, E2C / 64), 256, 0, stream>>>(X0, Wg1, H1, M, E2C);
    k_agginit<E2C><<<(M * E2C + 255) / 256, 256, 0, stream>>>(H1, dinv, bg1, A1, M);
    k_scatter<E2C, 2><<<dim3(EE / 2, Gc), 256, 0, stream>>>(el32, H1, dinv, A1, edge0);
    k_gemm<E2C, true><<<dim3((M + 31) / 32, E3C / 64), 256, 0, stream>>>(A1, Wg2, H2, M, E3C);
    k_agginit<E3C><<<(M * E3C + 255) / 256, 256, 0, stream>>>(H2, dinv, bg2, A2, M);
    k_scatter<E3C, 1><<<dim3(EE, Gc), 256, 0, stream>>>(el32, H2, dinv, A2, edge0);
    k_pool_atomic<<<dim3(Gc, PSLICE), 256, 0, stream>>>(A2, pp, g0);
  }
  k_pool_final<<<(NG * E3C + 255) / 256, 256, 0, stream>>>(pp, pooled);
  k_fc<<<NG, 64, 0, stream>>>(pooled, con, Wfc, bfc, xfc);
  k_build<<<27, 64, 0, stream>>>(muQ, sigQ, xfc, xA);
  for (int l = 0; l < NL; ++l) {
    k_attn<<<1, 512, 0, stream>>>(xA, xB,
        Wqkv + (size_t)l * 96 * ZZ, bqkv + l * 96,
        Wo + (size_t)l * ZZ * ZZ, bo + l * ZZ,
        l1s + l * ZZ, l1b + l * ZZ);
    k_ff<<<27 * BB, 256, 0, stream>>>(xB, xA,
        W1 + (size_t)l * FF_DIM * ZZ, b1 + l * FF_DIM,
        W2 + (size_t)l * ZZ * FF_DIM, b2 + l * ZZ,
        l2s + l * ZZ, l2b + l * ZZ);
  }
  k_out<<<(1856 + 255) / 256, 256, 0, stream>>>(xA, (float*)d_out);
}

// Round 13
// 1954.320 us; speedup vs baseline: 3.0260x; 3.0260x over previous
//
#include <hip/hip_runtime.h>
#include <hip/hip_bf16.h>
#include <math.h>

#define BB 2
#define SS 25
#define NNODE 5000
#define EE 15000
#define NG 50          /* B*S graphs */
#define ZZ 32
#define FF_DIM 1024
#define NL 4
#define NH 4
#define HD 8
#define E1C 64
#define E2C 128
#define E3C 256
#define CDIM 12
#define LN_EPS 1e-5f

// ---------- edge dtype detector (int64 vs int32 edge_list) ----------
__global__ void k_edetect(const int* __restrict__ w, int* __restrict__ eflag) {
  __shared__ int nz;
  if (threadIdx.x == 0) nz = 0;
  __syncthreads();
  int cnt = 0;
  for (int i = threadIdx.x; i < 2048; i += 256)
    if (w[2 * i + 1] != 0) cnt++;
  atomicAdd(&nz, cnt);
  __syncthreads();
  if (threadIdx.x == 0) *eflag = (nz < 100) ? 1 : 0;  // 1 => int64 layout
}

__global__ __launch_bounds__(256) void k_ecvt(const int* __restrict__ w,
    int* __restrict__ el32, int n, const int* __restrict__ eflag) {
  int i = blockIdx.x * 256 + threadIdx.x;
  if (i >= n) return;
  el32[i] = (*eflag) ? w[2 * i] : w[i];
}

// ---------------- skeleton embedding: relu(v @ Wemb^T + b) ----------------
__global__ __launch_bounds__(256) void k_emb(const float* __restrict__ v,
    const float* __restrict__ W, const float* __restrict__ b,
    float* __restrict__ X0, int M, int node0) {
  int idx = blockIdx.x * 256 + threadIdx.x;
  if (idx >= M * 64) return;
  int node = idx >> 6, o = idx & 63;
  const float* vp = v + (size_t)(node0 + node) * 3;
  float acc = b[o] + vp[0] * W[o * 3 + 0] + vp[1] * W[o * 3 + 1] + vp[2] * W[o * 3 + 2];
  X0[idx] = acc > 0.f ? acc : 0.f;
}

__global__ void k_zero_int(int* p, int n) {
  int i = blockIdx.x * 256 + threadIdx.x;
  if (i < n) p[i] = 0;
}

__global__ void k_deg(const int* __restrict__ el, int* __restrict__ cnt, int edge0) {
  int e = blockIdx.x * 256 + threadIdx.x;
  int g = blockIdx.y;
  if (e >= EE) return;
  int dst = el[(size_t)(edge0 + g * EE + e) * 2 + 1];
  if ((unsigned)dst >= NNODE) return;
  atomicAdd(&cnt[g * NNODE + dst], 1);
}

__global__ void k_dinv(const int* __restrict__ cnt, float* __restrict__ dinv, int M) {
  int i = blockIdx.x * 256 + threadIdx.x;
  if (i >= M) return;
  dinv[i] = rsqrtf((float)cnt[i] + 1.0f);
}

// ---- CSR build: per-graph exclusive scan of in-degrees -> off, cur ----
__global__ __launch_bounds__(256) void k_scan(const int* __restrict__ cnt,
    int* __restrict__ off, int* __restrict__ cur) {
  int g = blockIdx.x, t = threadIdx.x;
  __shared__ int part[256];
  const int CH = (NNODE + 255) / 256;  // 20
  int i0 = t * CH, i1 = i0 + CH > NNODE ? NNODE : i0 + CH;
  int s = 0;
  for (int i = i0; i < i1; ++i) s += cnt[g * NNODE + i];
  part[t] = s;
  __syncthreads();
  if (t == 0) {
    int run = 0;
    for (int i = 0; i < 256; ++i) { int v = part[i]; part[i] = run; run += v; }
  }
  __syncthreads();
  int run = part[t];
  for (int i = i0; i < i1; ++i) {
    off[g * NNODE + i] = run;
    cur[g * NNODE + i] = run;
    run += cnt[g * NNODE + i];
  }
}

// fill esrc sorted by dst (counting sort via cursor atomics)
__global__ __launch_bounds__(256) void k_csrfill(const int* __restrict__ el,
    int* __restrict__ cur, int* __restrict__ esrc, int edge0) {
  int e = blockIdx.x * 256 + threadIdx.x;
  int g = blockIdx.y;
  if (e >= EE) return;
  const int* ep = el + (size_t)(edge0 + g * EE + e) * 2;
  int src = ep[0], dst = ep[1];
  if ((unsigned)src >= NNODE || (unsigned)dst >= NNODE) return;
  int pos = atomicAdd(&cur[g * NNODE + dst], 1);
  esrc[(size_t)g * EE + pos] = src;
}

// ---- full-width GEMM: C[M,N] = (opt leaky)A[M,K] @ W[K,N], K-tiles of 32 ----
template <int K, int N, bool LEAKY>
__global__ __launch_bounds__(256) void k_gemmF(const float* __restrict__ A,
    const float* __restrict__ W, float* __restrict__ C, int M) {
  const int NCG = N / 4;       // col groups of 4
  const int TY  = 256 / NCG;   // row groups
  const int RPT = 32 / TY;     // rows per thread
  __shared__ float As[32][33];
  __shared__ float Ws[32][N];
  int m0 = blockIdx.x * 32;
  int tid = threadIdx.x;
  int cg = tid % NCG, ty = tid / NCG;
  int col0 = cg * 4;
  float acc[RPT][4];
#pragma unroll
  for (int r = 0; r < RPT; ++r) acc[r][0] = acc[r][1] = acc[r][2] = acc[r][3] = 0.f;
  for (int kt = 0; kt < K; kt += 32) {
    {
      int r = tid >> 3, k4 = (tid & 7) * 4;
      int row = m0 + r;
      float4 a = make_float4(0.f, 0.f, 0.f, 0.f);
      if (row < M) a = *(const float4*)&A[(size_t)row * K + kt + k4];
      if (LEAKY) {
        a.x = a.x > 0.f ? a.x : 0.15f * a.x;
        a.y = a.y > 0.f ? a.y : 0.15f * a.y;
        a.z = a.z > 0.f ? a.z : 0.15f * a.z;
        a.w = a.w > 0.f ? a.w : 0.15f * a.w;
      }
      As[r][k4 + 0] = a.x; As[r][k4 + 1] = a.y; As[r][k4 + 2] = a.z; As[r][k4 + 3] = a.w;
    }
    for (int i = tid; i < 32 * NCG; i += 256) {
      int k = i / NCG, c4 = (i % NCG) * 4;
      float4 w = *(const float4*)&W[(size_t)(kt + k) * N + c4];
      Ws[k][c4 + 0] = w.x; Ws[k][c4 + 1] = w.y; Ws[k][c4 + 2] = w.z; Ws[k][c4 + 3] = w.w;
    }
    __syncthreads();
#pragma unroll
    for (int k = 0; k < 32; ++k) {
      float w0 = Ws[k][col0], w1 = Ws[k][col0 + 1], w2 = Ws[k][col0 + 2], w3 = Ws[k][col0 + 3];
#pragma unroll
      for (int r = 0; r < RPT; ++r) {
        float a = As[ty * RPT + r][k];
        acc[r][0] += a * w0; acc[r][1] += a * w1; acc[r][2] += a * w2; acc[r][3] += a * w3;
      }
    }
    __syncthreads();
  }
#pragma unroll
  for (int r = 0; r < RPT; ++r) {
    int row = m0 + ty * RPT + r;
    if (row < M)
      *(float4*)&C[(size_t)row * N + col0] =
          make_float4(acc[r][0], acc[r][1], acc[r][2], acc[r][3]);
  }
}

// ---- order-preserving uint<->float for atomic max ----
__device__ __forceinline__ unsigned int f2u_mono(float f) {
  unsigned int u = __float_as_uint(f);
  return (u & 0x80000000u) ? ~u : (u | 0x80000000u);
}
__device__ __forceinline__ float u2f_mono(unsigned int m) {
  unsigned int u = (m & 0x80000000u) ? (m & 0x7FFFFFFFu) : ~m;
  return __uint_as_float(u);
}

__global__ void k_pool_init(unsigned int* pp, int n) {
  int i = blockIdx.x * 256 + threadIdx.x;
  if (i < n) pp[i] = 0u;
}

// ---- CSR gather: AGG[n,c] = sum_in H[src,c]*dinv[src]*dinv[n] + H[n,c]*dinv^2 + bias
// POOL: instead of writing AGG, fold running max -> atomicMax into pp (leaky after).
template <int C, bool POOL>
__global__ __launch_bounds__(256) void k_gather(const float* __restrict__ H,
    const float* __restrict__ dinv, const float* __restrict__ bias,
    const int* __restrict__ off, const int* __restrict__ cnt,
    const int* __restrict__ esrc, float* __restrict__ Aout,
    unsigned int* __restrict__ pp, int g0) {
  const int SUBS = 256 / C;   // 2 for C=128, 1 for C=256
  const int NPB = 50;         // nodes per block (grid.x = 100)
  int g = blockIdx.y;
  int gbase = g * NNODE;
  int n0 = blockIdx.x * NPB;
  int c = threadIdx.x % C, sub = threadIdx.x / C;
  float bc = bias[c];
  float mx = -1e30f;
  for (int i = sub; i < NPB; i += SUBS) {
    int n = gbase + n0 + i;
    float di = dinv[n];
    float acc = H[(size_t)n * C + c] * di * di + bc;
    int o = off[n], d = cnt[n];
    const int* ep = esrc + (size_t)g * EE + o;
    for (int j = 0; j < d; ++j) {
      int src = gbase + ep[j];
      acc += H[(size_t)src * C + c] * (dinv[src] * di);
    }
    if (POOL) mx = fmaxf(mx, acc);
    else Aout[(size_t)n * C + c] = acc;
  }
  if (POOL) atomicMax(&pp[(g0 + g) * C + c], f2u_mono(mx));
}

__global__ void k_pool_final(const unsigned int* __restrict__ pp,
    float* __restrict__ pooled) {
  int i = blockIdx.x * 256 + threadIdx.x;
  if (i >= NG * E3C) return;
  float m = u2f_mono(pp[i]);
  pooled[i] = m > 0.f ? m : 0.15f * m;  // leaky after max (monotone)
}

__global__ __launch_bounds__(64) void k_fc(const float* __restrict__ pooled,
    const float* __restrict__ con, const float* __restrict__ W,
    const float* __restrict__ bias, float* __restrict__ xfc) {
  int g = blockIdx.x;
  int z = threadIdx.x;
  if (z >= ZZ) return;
  int b = g / SS;
  float acc = bias[z];
  const float* pr = pooled + g * E3C;
  for (int i = 0; i < E3C; ++i) acc += pr[i] * W[i * ZZ + z];
  for (int i = 0; i < CDIM; ++i) acc += con[b * CDIM + i] * W[(E3C + i) * ZZ + z];
  xfc[g * ZZ + z] = acc > 0.f ? acc : 0.f;
}

__global__ __launch_bounds__(64) void k_build(const float* __restrict__ muQ,
    const float* __restrict__ sigQ, const float* __restrict__ xfc,
    float* __restrict__ xA) {
  int t = blockIdx.x;
  int z = threadIdx.x & 31, b = threadIdx.x >> 5;
  float val;
  if (t == 0)      val = muQ[z];
  else if (t == 1) val = sigQ[z];
  else             val = xfc[(b * SS + (t - 2)) * ZZ + z];
  int i = z >> 1;
  float freq = expf(-(float)(2 * i) * (logf(10000.f) / 32.f));
  float ang = (float)t * freq;
  float pe = (z & 1) ? cosf(ang) : sinf(ang);
  xA[(t * BB + b) * ZZ + z] = val + pe;
}

// attention half: xout = LN1(x + proj(attn(x)))
__global__ __launch_bounds__(512) void k_attn(const float* __restrict__ xin,
    float* __restrict__ xout, const float* __restrict__ Wqkv,
    const float* __restrict__ bqkv, const float* __restrict__ Wo,
    const float* __restrict__ bo, const float* __restrict__ l1s,
    const float* __restrict__ l1b) {
  const int T = SS + 2, TB = T * BB;  // 27, 54
  __shared__ float xs[54 * 32];
  __shared__ float qk[54 * 96];
  __shared__ float os[54 * 32];
  __shared__ float ys[54 * 32];
  int tid = threadIdx.x;
  for (int i = tid; i < TB * ZZ; i += 512) xs[i] = xin[i];
  __syncthreads();
  for (int i = tid; i < TB * 96; i += 512) {
    int tb = i / 96, j = i % 96;
    float acc = bqkv[j];
#pragma unroll
    for (int d = 0; d < ZZ; ++d) acc += xs[tb * ZZ + d] * Wqkv[j * ZZ + d];
    qk[i] = acc;
  }
  __syncthreads();
  if (tid < BB * NH * T) {
    int t = tid % T;
    int bh = tid / T;
    int h = bh % NH, b = bh / NH;
    float q[HD];
#pragma unroll
    for (int d = 0; d < HD; ++d) q[d] = qk[(t * BB + b) * 96 + h * HD + d];
    float sc[27];
    float mx = -1e30f;
#pragma unroll
    for (int s = 0; s < T; ++s) {
      float a = 0.f;
#pragma unroll
      for (int d = 0; d < HD; ++d) a += q[d] * qk[(s * BB + b) * 96 + 32 + h * HD + d];
      a *= 0.35355339059327373f;
      sc[s] = a;
      mx = fmaxf(mx, a);
    }
    float sum = 0.f;
#pragma unroll
    for (int s = 0; s < T; ++s) { float e = expf(sc[s] - mx); sc[s] = e; sum += e; }
    float inv = 1.f / sum;
    float o[HD];
#pragma unroll
    for (int d = 0; d < HD; ++d) o[d] = 0.f;
#pragma unroll
    for (int s = 0; s < T; ++s) {
      float a = sc[s] * inv;
#pragma unroll
      for (int d = 0; d < HD; ++d) o[d] += a * qk[(s * BB + b) * 96 + 64 + h * HD + d];
    }
#pragma unroll
    for (int d = 0; d < HD; ++d) os[(t * BB + b) * ZZ + h * HD + d] = o[d];
  }
  __syncthreads();
  for (int i = tid; i < TB * ZZ; i += 512) {
    int tb = i / ZZ, j = i % ZZ;
    float acc = bo[j];
#pragma unroll
    for (int d = 0; d < ZZ; ++d) acc += os[tb * ZZ + d] * Wo[j * ZZ + d];
    ys[i] = xs[i] + acc;
  }
  __syncthreads();
  if (tid < TB) {
    float m = 0.f;
#pragma unroll
    for (int z = 0; z < ZZ; ++z) m += ys[tid * ZZ + z];
    m *= (1.f / ZZ);
    float vv = 0.f;
#pragma unroll
    for (int z = 0; z < ZZ; ++z) { float d = ys[tid * ZZ + z] - m; vv += d * d; }
    float r = rsqrtf(vv * (1.f / ZZ) + LN_EPS);
    for (int z = 0; z < ZZ; ++z)
      xout[tid * ZZ + z] = (ys[tid * ZZ + z] - m) * r * l1s[z] + l1b[z];
  }
}

// FF half: xout = LN2(x + W2 gelu(W1 x))
__global__ __launch_bounds__(256) void k_ff(const float* __restrict__ xin,
    float* __restrict__ xout, const float* __restrict__ W1,
    const float* __restrict__ b1, const float* __restrict__ W2,
    const float* __restrict__ b2, const float* __restrict__ l2s,
    const float* __restrict__ l2b) {
  int tb = blockIdx.x;
  __shared__ float xt[ZZ];
  __shared__ float h[FF_DIM];
  __shared__ float yo[ZZ];
  __shared__ float stats[2];
  int tid = threadIdx.x;
  if (tid < ZZ) xt[tid] = xin[tb * ZZ + tid];
  __syncthreads();
  for (int f = tid; f < FF_DIM; f += 256) {
    float acc = b1[f];
#pragma unroll
    for (int d = 0; d < ZZ; ++d) acc += xt[d] * W1[f * ZZ + d];
    h[f] = 0.5f * acc * (1.f + erff(acc * 0.70710678118654752f));
  }
  __syncthreads();
  int wid = tid >> 6, lane = tid & 63;
  for (int o = wid; o < ZZ; o += 4) {
    float p = 0.f;
    for (int f = lane; f < FF_DIM; f += 64) p += h[f] * W2[o * FF_DIM + f];
#pragma unroll
    for (int off = 32; off; off >>= 1) p += __shfl_down(p, off);
    if (lane == 0) yo[o] = p + b2[o];
  }
  __syncthreads();
  if (tid == 0) {
    float m = 0.f;
    for (int z = 0; z < ZZ; ++z) { yo[z] += xt[z]; m += yo[z]; }
    m *= (1.f / ZZ);
    float vv = 0.f;
    for (int z = 0; z < ZZ; ++z) { float d = yo[z] - m; vv += d * d; }
    stats[0] = m;
    stats[1] = rsqrtf(vv * (1.f / ZZ) + LN_EPS);
  }
  __syncthreads();
  if (tid < ZZ)
    xout[tb * ZZ + tid] = (yo[tid] - stats[0]) * stats[1] * l2s[tid] + l2b[tid];
}

// output dtype = FLOAT32 (validated r10)
__global__ void k_out(const float* __restrict__ xA, float* __restrict__ out) {
  int i = blockIdx.x * 256 + threadIdx.x;
  if (i >= 1856) return;
  out[i] = (i < 128) ? xA[i] : xA[i - 128];
}

extern "C" void kernel_launch(void* const* d_in, const int* in_sizes, int n_in,
                              void* d_out, int out_size, void* d_ws, size_t ws_size,
                              hipStream_t stream) {
  const float* v    = (const float*)d_in[0];
  const int*   el   = (const int*)d_in[1];
  const float* con  = (const float*)d_in[2];
  const float* Wemb = (const float*)d_in[3];
  const float* bemb = (const float*)d_in[4];
  const float* Wg1  = (const float*)d_in[5];
  const float* bg1  = (const float*)d_in[6];
  const float* Wg2  = (const float*)d_in[7];
  const float* bg2  = (const float*)d_in[8];
  const float* Wfc  = (const float*)d_in[9];
  const float* bfc  = (const float*)d_in[10];
  const float* muQ  = (const float*)d_in[11];
  const float* sigQ = (const float*)d_in[12];
  const float* Wqkv = (const float*)d_in[13];
  const float* bqkv = (const float*)d_in[14];
  const float* Wo   = (const float*)d_in[15];
  const float* bo   = (const float*)d_in[16];
  const float* l1s  = (const float*)d_in[17];
  const float* l1b  = (const float*)d_in[18];
  const float* l2s  = (const float*)d_in[19];
  const float* l2b  = (const float*)d_in[20];
  const float* W1   = (const float*)d_in[21];
  const float* b1   = (const float*)d_in[22];
  const float* W2   = (const float*)d_in[23];
  const float* b2   = (const float*)d_in[24];

  // ---- workspace layout ----
  char* base = (char*)d_ws;
  int* eflag = (int*)base;
  float* pooled = (float*)(base + 256);    // 50*256
  float* xfc    = pooled + NG * E3C;
  float* xA     = xfc + NG * ZZ;
  float* xB     = xA + 27 * BB * ZZ;
  unsigned int* pp = (unsigned int*)(xB + 27 * BB * ZZ);  // 50*256

  int* el32 = (int*)(base + (2u << 20));   // 1.5M ints = 6MB (ends at +8MB)
  char* cb  = base + (16u << 20);          // chunk region

  k_edetect<<<1, 256, 0, stream>>>(el, eflag);
  k_ecvt<<<(NG * EE * 2 + 255) / 256, 256, 0, stream>>>(el, el32, NG * EE * 2, eflag);

  // per-node bytes: X0 256 + H1 512 + A1 512 + H2 1024 + cnt/dinv/off/cur 16 + esrc 12 = 2332
  int Gc = 1;
  const int opts[5] = {50, 25, 10, 5, 1};
  for (int oi = 0; oi < 5; ++oi) {
    size_t need = (size_t)(16u << 20) + (size_t)opts[oi] * NNODE * 2400ull;
    if (need <= ws_size) { Gc = opts[oi]; break; }
  }
  int M = Gc * NNODE;
  float* X0  = (float*)cb;
  float* H1  = X0 + (size_t)M * E1C;
  float* A1  = H1 + (size_t)M * E2C;
  float* H2  = A1 + (size_t)M * E2C;
  int*   cnt = (int*)(H2 + (size_t)M * E3C);
  float* dinv = (float*)(cnt + M);
  int*   off  = (int*)(dinv + M);
  int*   cur  = off + M;
  int*   esrc = cur + M;                   // Gc*EE ints

  k_pool_init<<<(NG * E3C + 255) / 256, 256, 0, stream>>>(pp, NG * E3C);
  for (int g0 = 0; g0 < NG; g0 += Gc) {
    int node0 = g0 * NNODE, edge0 = g0 * EE;
    k_emb<<<(M * 64 + 255) / 256, 256, 0, stream>>>(v, Wemb, bemb, X0, M, node0);
    k_zero_int<<<(M + 255) / 256, 256, 0, stream>>>(cnt, M);
    k_deg<<<dim3((EE + 255) / 256, Gc), 256, 0, stream>>>(el32, cnt, edge0);
    k_dinv<<<(M + 255) / 256, 256, 0, stream>>>(cnt, dinv, M);
    k_scan<<<Gc, 256, 0, stream>>>(cnt, off, cur);
    k_csrfill<<<dim3((EE + 255) / 256, Gc), 256, 0, stream>>>(el32, cur, esrc, edge0);
    k_gemmF<E1C, E2C, false><<<(M + 31) / 32, 256, 0, stream>>>(X0, Wg1, H1, M);
    k_gather<E2C, false><<<dim3(NNODE / 50, Gc), 256, 0, stream>>>(
        H1, dinv, bg1, off, cnt, esrc, A1, nullptr, g0);
    k_gemmF<E2C, E3C, true><<<(M + 31) / 32, 256, 0, stream>>>(A1, Wg2, H2, M);
    k_gather<E3C, true><<<dim3(NNODE / 50, Gc), 256, 0, stream>>>(
        H2, dinv, bg2, off, cnt, esrc, nullptr, pp, g0);
  }
  k_pool_final<<<(NG * E3C + 255) / 256, 256, 0, stream>>>(pp, pooled);
  k_fc<<<NG, 64, 0, stream>>>(pooled, con, Wfc, bfc, xfc);
  k_build<<<27, 64, 0, stream>>>(muQ, sigQ, xfc, xA);
  for (int l = 0; l < NL; ++l) {
    k_attn<<<1, 512, 0, stream>>>(xA, xB,
        Wqkv + (size_t)l * 96 * ZZ, bqkv + l * 96,
        Wo + (size_t)l * ZZ * ZZ, bo + l * ZZ,
        l1s + l * ZZ, l1b + l * ZZ);
    k_ff<<<27 * BB, 256, 0, stream>>>(xB, xA,
        W1 + (size_t)l * FF_DIM * ZZ, b1 + l * FF_DIM,
        W2 + (size_t)l * ZZ * FF_DIM, b2 + l * ZZ,
        l2s + l * ZZ, l2b + l * ZZ);
  }
  k_out<<<(1856 + 255) / 256, 256, 0, stream>>>(xA, (float*)d_out);
}

// Round 14
// 1208.897 us; speedup vs baseline: 4.8919x; 1.6166x over previous
//
#include <hip/hip_runtime.h>
#include <hip/hip_bf16.h>
#include <math.h>

#define BB 2
#define SS 25
#define NNODE 5000
#define EE 15000
#define NG 50          /* B*S graphs */
#define ZZ 32
#define FF_DIM 1024
#define NL 4
#define NH 4
#define HD 8
#define E1C 64
#define E2C 128
#define E3C 256
#define CDIM 12
#define LN_EPS 1e-5f
#define GTILES ((NNODE + 31) / 32)   /* 157 row-tiles per graph */

// ---------- edge dtype detector (int64 vs int32 edge_list) ----------
__global__ void k_edetect(const int* __restrict__ w, int* __restrict__ eflag) {
  __shared__ int nz;
  if (threadIdx.x == 0) nz = 0;
  __syncthreads();
  int cnt = 0;
  for (int i = threadIdx.x; i < 2048; i += 256)
    if (w[2 * i + 1] != 0) cnt++;
  atomicAdd(&nz, cnt);
  __syncthreads();
  if (threadIdx.x == 0) *eflag = (nz < 100) ? 1 : 0;  // 1 => int64 layout
}

__global__ __launch_bounds__(256) void k_ecvt(const int* __restrict__ w,
    int* __restrict__ el32, int n, const int* __restrict__ eflag) {
  int i = blockIdx.x * 256 + threadIdx.x;
  if (i >= n) return;
  el32[i] = (*eflag) ? w[2 * i] : w[i];
}

// ---------------- skeleton embedding: relu(v @ Wemb^T + b) ----------------
__global__ __launch_bounds__(256) void k_emb(const float* __restrict__ v,
    const float* __restrict__ W, const float* __restrict__ b,
    float* __restrict__ X0, int M, int node0) {
  int idx = blockIdx.x * 256 + threadIdx.x;
  if (idx >= M * 64) return;
  int node = idx >> 6, o = idx & 63;
  const float* vp = v + (size_t)(node0 + node) * 3;
  float acc = b[o] + vp[0] * W[o * 3 + 0] + vp[1] * W[o * 3 + 1] + vp[2] * W[o * 3 + 2];
  X0[idx] = acc > 0.f ? acc : 0.f;
}

__global__ void k_zero_int(int* p, int n) {
  int i = blockIdx.x * 256 + threadIdx.x;
  if (i < n) p[i] = 0;
}

__global__ void k_deg(const int* __restrict__ el, int* __restrict__ cnt, int edge0) {
  int e = blockIdx.x * 256 + threadIdx.x;
  int g = blockIdx.y;
  if (e >= EE) return;
  int dst = el[(size_t)(edge0 + g * EE + e) * 2 + 1];
  if ((unsigned)dst >= NNODE) return;
  atomicAdd(&cnt[g * NNODE + dst], 1);
}

// ---- CSR build: per-graph exclusive scan of in-degrees -> off, cur (+dinv) ----
__global__ __launch_bounds__(256) void k_scan(const int* __restrict__ cnt,
    int* __restrict__ off, int* __restrict__ cur, float* __restrict__ dinv) {
  int g = blockIdx.x, t = threadIdx.x;
  __shared__ int part[256];
  const int CH = (NNODE + 255) / 256;  // 20
  int i0 = t * CH, i1 = i0 + CH > NNODE ? NNODE : i0 + CH;
  int s = 0;
  for (int i = i0; i < i1; ++i) s += cnt[g * NNODE + i];
  part[t] = s;
  __syncthreads();
  if (t == 0) {
    int run = 0;
    for (int i = 0; i < 256; ++i) { int v = part[i]; part[i] = run; run += v; }
  }
  __syncthreads();
  int run = part[t];
  for (int i = i0; i < i1; ++i) {
    int cv = cnt[g * NNODE + i];
    off[g * NNODE + i] = run;
    cur[g * NNODE + i] = run;
    dinv[g * NNODE + i] = rsqrtf((float)cv + 1.0f);
    run += cv;
  }
}

// fill esrc sorted by dst (counting sort via cursor atomics)
__global__ __launch_bounds__(256) void k_csrfill(const int* __restrict__ el,
    int* __restrict__ cur, int* __restrict__ esrc, int edge0) {
  int e = blockIdx.x * 256 + threadIdx.x;
  int g = blockIdx.y;
  if (e >= EE) return;
  const int* ep = el + (size_t)(edge0 + g * EE + e) * 2;
  int src = ep[0], dst = ep[1];
  if ((unsigned)src >= NNODE || (unsigned)dst >= NNODE) return;
  int pos = atomicAdd(&cur[g * NNODE + dst], 1);
  esrc[(size_t)g * EE + pos] = src;
}

// ---- normalized-adjacency gather (pre-matmul): T = S~ . X  (no bias) ----
// T[n,c] = X[n,c]*dinv[n]^2 + sum_in X[src,c]*dinv[src]*dinv[n]
template <int C>
__global__ __launch_bounds__(256) void k_gatherX(const float* __restrict__ X,
    const float* __restrict__ dinv, const int* __restrict__ off,
    const int* __restrict__ cnt, const int* __restrict__ esrc,
    float* __restrict__ T) {
  const int SUBS = 256 / C;   // 4 for C=64, 2 for C=128
  const int NPB = 10;         // nodes per block (grid.x = 500)
  int g = blockIdx.y;
  int gbase = g * NNODE;
  int n0 = blockIdx.x * NPB;
  int c = threadIdx.x % C, sub = threadIdx.x / C;
  for (int i = sub; i < NPB; i += SUBS) {
    int n = gbase + n0 + i;
    float di = dinv[n];
    float acc = X[(size_t)n * C + c] * di * di;
    int o = off[n], d = cnt[n];
    const int* ep = esrc + (size_t)g * EE + o;
    for (int j = 0; j < d; ++j) {
      int src = gbase + ep[j];
      acc += X[(size_t)src * C + c] * (dinv[src] * di);
    }
    T[(size_t)n * C + c] = acc;
  }
}

// ---- order-preserving uint<->float for atomic max ----
__device__ __forceinline__ unsigned int f2u_mono(float f) {
  unsigned int u = __float_as_uint(f);
  return (u & 0x80000000u) ? ~u : (u | 0x80000000u);
}
__device__ __forceinline__ float u2f_mono(unsigned int m) {
  unsigned int u = (m & 0x80000000u) ? (m & 0x7FFFFFFFu) : ~m;
  return __uint_as_float(u);
}

__global__ void k_pool_init(unsigned int* pp, int n) {
  int i = blockIdx.x * 256 + threadIdx.x;
  if (i < n) pp[i] = 0u;
}

// ---- GEMM + epilogue: C = T.W + bias; LEAKYOUT: leaky on output;
// POOL: no store -> block max per column -> atomicMax pp[graph] ----
// grid = (GTILES, Gc): each block owns 32 rows of ONE graph.
template <int K, int N, bool LEAKYOUT, bool POOL>
__global__ __launch_bounds__(256) void k_gemmE(const float* __restrict__ T,
    const float* __restrict__ W, const float* __restrict__ bias,
    float* __restrict__ Cout, unsigned int* __restrict__ pp, int g0) {
  const int NCG = N / 4;       // col groups of 4
  const int TY  = 256 / NCG;   // row groups
  const int RPT = 32 / TY;     // rows per thread
  __shared__ float As[32][33];
  __shared__ float Ws[32][N];
  __shared__ float smax[TY][N];
  int g = blockIdx.y;
  int m0 = blockIdx.x * 32;                  // local row base
  size_t rbase = (size_t)g * NNODE + m0;
  int nvalid = NNODE - m0; if (nvalid > 32) nvalid = 32;
  int tid = threadIdx.x;
  int cg = tid % NCG, ty = tid / NCG;
  int col0 = cg * 4;
  float acc[RPT][4];
#pragma unroll
  for (int r = 0; r < RPT; ++r) acc[r][0] = acc[r][1] = acc[r][2] = acc[r][3] = 0.f;
  for (int kt = 0; kt < K; kt += 32) {
    {
      int r = tid >> 3, k4 = (tid & 7) * 4;
      float4 a = make_float4(0.f, 0.f, 0.f, 0.f);
      if (r < nvalid) a = *(const float4*)&T[(rbase + r) * K + kt + k4];
      As[r][k4 + 0] = a.x; As[r][k4 + 1] = a.y; As[r][k4 + 2] = a.z; As[r][k4 + 3] = a.w;
    }
    for (int i = tid; i < 32 * NCG; i += 256) {
      int k = i / NCG, c4 = (i % NCG) * 4;
      float4 w = *(const float4*)&W[(size_t)(kt + k) * N + c4];
      Ws[k][c4 + 0] = w.x; Ws[k][c4 + 1] = w.y; Ws[k][c4 + 2] = w.z; Ws[k][c4 + 3] = w.w;
    }
    __syncthreads();
#pragma unroll
    for (int k = 0; k < 32; ++k) {
      float w0 = Ws[k][col0], w1 = Ws[k][col0 + 1], w2 = Ws[k][col0 + 2], w3 = Ws[k][col0 + 3];
#pragma unroll
      for (int r = 0; r < RPT; ++r) {
        float a = As[ty * RPT + r][k];
        acc[r][0] += a * w0; acc[r][1] += a * w1; acc[r][2] += a * w2; acc[r][3] += a * w3;
      }
    }
    __syncthreads();
  }
  float b0 = bias[col0], b1 = bias[col0 + 1], b2 = bias[col0 + 2], b3 = bias[col0 + 3];
  if (!POOL) {
#pragma unroll
    for (int r = 0; r < RPT; ++r) {
      int rl = ty * RPT + r;
      if (rl < nvalid) {
        float v0 = acc[r][0] + b0, v1 = acc[r][1] + b1;
        float v2 = acc[r][2] + b2, v3 = acc[r][3] + b3;
        if (LEAKYOUT) {
          v0 = v0 > 0.f ? v0 : 0.15f * v0;
          v1 = v1 > 0.f ? v1 : 0.15f * v1;
          v2 = v2 > 0.f ? v2 : 0.15f * v2;
          v3 = v3 > 0.f ? v3 : 0.15f * v3;
        }
        *(float4*)&Cout[(rbase + rl) * N + col0] = make_float4(v0, v1, v2, v3);
      }
    }
  } else {
    float m0x = -1e30f, m1x = -1e30f, m2x = -1e30f, m3x = -1e30f;
#pragma unroll
    for (int r = 0; r < RPT; ++r) {
      int rl = ty * RPT + r;
      if (rl < nvalid) {
        m0x = fmaxf(m0x, acc[r][0] + b0);
        m1x = fmaxf(m1x, acc[r][1] + b1);
        m2x = fmaxf(m2x, acc[r][2] + b2);
        m3x = fmaxf(m3x, acc[r][3] + b3);
      }
    }
    smax[ty][col0 + 0] = m0x; smax[ty][col0 + 1] = m1x;
    smax[ty][col0 + 2] = m2x; smax[ty][col0 + 3] = m3x;
    __syncthreads();
    if (ty == 0) {
#pragma unroll
      for (int j = 0; j < 4; ++j) {
        float m = smax[0][col0 + j];
#pragma unroll
        for (int t = 1; t < TY; ++t) m = fmaxf(m, smax[t][col0 + j]);
        atomicMax(&pp[(g0 + g) * N + col0 + j], f2u_mono(m));
      }
    }
  }
}

__global__ void k_pool_final(const unsigned int* __restrict__ pp,
    float* __restrict__ pooled) {
  int i = blockIdx.x * 256 + threadIdx.x;
  if (i >= NG * E3C) return;
  float m = u2f_mono(pp[i]);
  pooled[i] = m > 0.f ? m : 0.15f * m;  // leaky after max (monotone)
}

__global__ __launch_bounds__(64) void k_fc(const float* __restrict__ pooled,
    const float* __restrict__ con, const float* __restrict__ W,
    const float* __restrict__ bias, float* __restrict__ xfc) {
  int g = blockIdx.x;
  int z = threadIdx.x;
  if (z >= ZZ) return;
  int b = g / SS;
  float acc = bias[z];
  const float* pr = pooled + g * E3C;
  for (int i = 0; i < E3C; ++i) acc += pr[i] * W[i * ZZ + z];
  for (int i = 0; i < CDIM; ++i) acc += con[b * CDIM + i] * W[(E3C + i) * ZZ + z];
  xfc[g * ZZ + z] = acc > 0.f ? acc : 0.f;
}

__global__ __launch_bounds__(64) void k_build(const float* __restrict__ muQ,
    const float* __restrict__ sigQ, const float* __restrict__ xfc,
    float* __restrict__ xA) {
  int t = blockIdx.x;
  int z = threadIdx.x & 31, b = threadIdx.x >> 5;
  float val;
  if (t == 0)      val = muQ[z];
  else if (t == 1) val = sigQ[z];
  else             val = xfc[(b * SS + (t - 2)) * ZZ + z];
  int i = z >> 1;
  float freq = expf(-(float)(2 * i) * (logf(10000.f) / 32.f));
  float ang = (float)t * freq;
  float pe = (z & 1) ? cosf(ang) : sinf(ang);
  xA[(t * BB + b) * ZZ + z] = val + pe;
}

// attention half: xout = LN1(x + proj(attn(x)))
__global__ __launch_bounds__(512) void k_attn(const float* __restrict__ xin,
    float* __restrict__ xout, const float* __restrict__ Wqkv,
    const float* __restrict__ bqkv, const float* __restrict__ Wo,
    const float* __restrict__ bo, const float* __restrict__ l1s,
    const float* __restrict__ l1b) {
  const int T = SS + 2, TB = T * BB;  // 27, 54
  __shared__ float xs[54 * 32];
  __shared__ float qk[54 * 96];
  __shared__ float os[54 * 32];
  __shared__ float ys[54 * 32];
  int tid = threadIdx.x;
  for (int i = tid; i < TB * ZZ; i += 512) xs[i] = xin[i];
  __syncthreads();
  for (int i = tid; i < TB * 96; i += 512) {
    int tb = i / 96, j = i % 96;
    float acc = bqkv[j];
#pragma unroll
    for (int d = 0; d < ZZ; ++d) acc += xs[tb * ZZ + d] * Wqkv[j * ZZ + d];
    qk[i] = acc;
  }
  __syncthreads();
  if (tid < BB * NH * T) {
    int t = tid % T;
    int bh = tid / T;
    int h = bh % NH, b = bh / NH;
    float q[HD];
#pragma unroll
    for (int d = 0; d < HD; ++d) q[d] = qk[(t * BB + b) * 96 + h * HD + d];
    float sc[27];
    float mx = -1e30f;
#pragma unroll
    for (int s = 0; s < T; ++s) {
      float a = 0.f;
#pragma unroll
      for (int d = 0; d < HD; ++d) a += q[d] * qk[(s * BB + b) * 96 + 32 + h * HD + d];
      a *= 0.35355339059327373f;
      sc[s] = a;
      mx = fmaxf(mx, a);
    }
    float sum = 0.f;
#pragma unroll
    for (int s = 0; s < T; ++s) { float e = expf(sc[s] - mx); sc[s] = e; sum += e; }
    float inv = 1.f / sum;
    float o[HD];
#pragma unroll
    for (int d = 0; d < HD; ++d) o[d] = 0.f;
#pragma unroll
    for (int s = 0; s < T; ++s) {
      float a = sc[s] * inv;
#pragma unroll
      for (int d = 0; d < HD; ++d) o[d] += a * qk[(s * BB + b) * 96 + 64 + h * HD + d];
    }
#pragma unroll
    for (int d = 0; d < HD; ++d) os[(t * BB + b) * ZZ + h * HD + d] = o[d];
  }
  __syncthreads();
  for (int i = tid; i < TB * ZZ; i += 512) {
    int tb = i / ZZ, j = i % ZZ;
    float acc = bo[j];
#pragma unroll
    for (int d = 0; d < ZZ; ++d) acc += os[tb * ZZ + d] * Wo[j * ZZ + d];
    ys[i] = xs[i] + acc;
  }
  __syncthreads();
  if (tid < TB) {
    float m = 0.f;
#pragma unroll
    for (int z = 0; z < ZZ; ++z) m += ys[tid * ZZ + z];
    m *= (1.f / ZZ);
    float vv = 0.f;
#pragma unroll
    for (int z = 0; z < ZZ; ++z) { float d = ys[tid * ZZ + z] - m; vv += d * d; }
    float r = rsqrtf(vv * (1.f / ZZ) + LN_EPS);
    for (int z = 0; z < ZZ; ++z)
      xout[tid * ZZ + z] = (ys[tid * ZZ + z] - m) * r * l1s[z] + l1b[z];
  }
}

// FF half: xout = LN2(x + W2 gelu(W1 x))
__global__ __launch_bounds__(256) void k_ff(const float* __restrict__ xin,
    float* __restrict__ xout, const float* __restrict__ W1,
    const float* __restrict__ b1, const float* __restrict__ W2,
    const float* __restrict__ b2, const float* __restrict__ l2s,
    const float* __restrict__ l2b) {
  int tb = blockIdx.x;
  __shared__ float xt[ZZ];
  __shared__ float h[FF_DIM];
  __shared__ float yo[ZZ];
  __shared__ float stats[2];
  int tid = threadIdx.x;
  if (tid < ZZ) xt[tid] = xin[tb * ZZ + tid];
  __syncthreads();
  for (int f = tid; f < FF_DIM; f += 256) {
    float acc = b1[f];
#pragma unroll
    for (int d = 0; d < ZZ; ++d) acc += xt[d] * W1[f * ZZ + d];
    h[f] = 0.5f * acc * (1.f + erff(acc * 0.70710678118654752f));
  }
  __syncthreads();
  int wid = tid >> 6, lane = tid & 63;
  for (int o = wid; o < ZZ; o += 4) {
    float p = 0.f;
    for (int f = lane; f < FF_DIM; f += 64) p += h[f] * W2[o * FF_DIM + f];
#pragma unroll
    for (int off = 32; off; off >>= 1) p += __shfl_down(p, off);
    if (lane == 0) yo[o] = p + b2[o];
  }
  __syncthreads();
  if (tid == 0) {
    float m = 0.f;
    for (int z = 0; z < ZZ; ++z) { yo[z] += xt[z]; m += yo[z]; }
    m *= (1.f / ZZ);
    float vv = 0.f;
    for (int z = 0; z < ZZ; ++z) { float d = yo[z] - m; vv += d * d; }
    stats[0] = m;
    stats[1] = rsqrtf(vv * (1.f / ZZ) + LN_EPS);
  }
  __syncthreads();
  if (tid < ZZ)
    xout[tb * ZZ + tid] = (yo[tid] - stats[0]) * stats[1] * l2s[tid] + l2b[tid];
}

// output dtype = FLOAT32 (validated r10)
__global__ void k_out(const float* __restrict__ xA, float* __restrict__ out) {
  int i = blockIdx.x * 256 + threadIdx.x;
  if (i >= 1856) return;
  out[i] = (i < 128) ? xA[i] : xA[i - 128];
}

extern "C" void kernel_launch(void* const* d_in, const int* in_sizes, int n_in,
                              void* d_out, int out_size, void* d_ws, size_t ws_size,
                              hipStream_t stream) {
  const float* v    = (const float*)d_in[0];
  const int*   el   = (const int*)d_in[1];
  const float* con  = (const float*)d_in[2];
  const float* Wemb = (const float*)d_in[3];
  const float* bemb = (const float*)d_in[4];
  const float* Wg1  = (const float*)d_in[5];
  const float* bg1  = (const float*)d_in[6];
  const float* Wg2  = (const float*)d_in[7];
  const float* bg2  = (const float*)d_in[8];
  const float* Wfc  = (const float*)d_in[9];
  const float* bfc  = (const float*)d_in[10];
  const float* muQ  = (const float*)d_in[11];
  const float* sigQ = (const float*)d_in[12];
  const float* Wqkv = (const float*)d_in[13];
  const float* bqkv = (const float*)d_in[14];
  const float* Wo   = (const float*)d_in[15];
  const float* bo   = (const float*)d_in[16];
  const float* l1s  = (const float*)d_in[17];
  const float* l1b  = (const float*)d_in[18];
  const float* l2s  = (const float*)d_in[19];
  const float* l2b  = (const float*)d_in[20];
  const float* W1   = (const float*)d_in[21];
  const float* b1   = (const float*)d_in[22];
  const float* W2   = (const float*)d_in[23];
  const float* b2   = (const float*)d_in[24];

  // ---- workspace layout ----
  char* base = (char*)d_ws;
  int* eflag = (int*)base;
  float* pooled = (float*)(base + 256);    // 50*256
  float* xfc    = pooled + NG * E3C;
  float* xA     = xfc + NG * ZZ;
  float* xB     = xA + 27 * BB * ZZ;
  unsigned int* pp = (unsigned int*)(xB + 27 * BB * ZZ);  // 50*256

  int* el32 = (int*)(base + (2u << 20));   // 1.5M ints = 6MB (ends at +8MB)
  char* cb  = base + (16u << 20);          // chunk region

  k_edetect<<<1, 256, 0, stream>>>(el, eflag);
  k_ecvt<<<(NG * EE * 2 + 255) / 256, 256, 0, stream>>>(el, el32, NG * EE * 2, eflag);

  // per-node bytes: X0 256 + T1 256 + L1 512 + T2 512 + cnt/dinv/off/cur 16 + esrc 12 = 1564
  int Gc = 1;
  const int opts[5] = {50, 25, 10, 5, 1};
  for (int oi = 0; oi < 5; ++oi) {
    size_t need = (size_t)(16u << 20) + (size_t)opts[oi] * NNODE * 1600ull;
    if (need <= ws_size) { Gc = opts[oi]; break; }
  }
  int M = Gc * NNODE;
  float* X0  = (float*)cb;
  float* T1  = X0 + (size_t)M * E1C;
  float* L1  = T1 + (size_t)M * E1C;
  float* T2  = L1 + (size_t)M * E2C;
  int*   cnt = (int*)(T2 + (size_t)M * E2C);
  float* dinv = (float*)(cnt + M);
  int*   off  = (int*)(dinv + M);
  int*   cur  = off + M;
  int*   esrc = cur + M;                   // Gc*EE ints

  k_pool_init<<<(NG * E3C + 255) / 256, 256, 0, stream>>>(pp, NG * E3C);
  for (int g0 = 0; g0 < NG; g0 += Gc) {
    int node0 = g0 * NNODE, edge0 = g0 * EE;
    k_emb<<<(M * 64 + 255) / 256, 256, 0, stream>>>(v, Wemb, bemb, X0, M, node0);
    k_zero_int<<<(M + 255) / 256, 256, 0, stream>>>(cnt, M);
    k_deg<<<dim3((EE + 255) / 256, Gc), 256, 0, stream>>>(el32, cnt, edge0);
    k_scan<<<Gc, 256, 0, stream>>>(cnt, off, cur, dinv);
    k_csrfill<<<dim3((EE + 255) / 256, Gc), 256, 0, stream>>>(el32, cur, esrc, edge0);
    // layer 1: T1 = S~.X0 ; L1 = leaky(T1.Wg1 + bg1)
    k_gatherX<E1C><<<dim3(NNODE / 10, Gc), 256, 0, stream>>>(X0, dinv, off, cnt, esrc, T1);
    k_gemmE<E1C, E2C, true, false><<<dim3(GTILES, Gc), 256, 0, stream>>>(
        T1, Wg1, bg1, L1, nullptr, g0);
    // layer 2: T2 = S~.L1 ; pool(T2.Wg2 + bg2) -> pp (no materialization)
    k_gatherX<E2C><<<dim3(NNODE / 10, Gc), 256, 0, stream>>>(L1, dinv, off, cnt, esrc, T2);
    k_gemmE<E2C, E3C, false, true><<<dim3(GTILES, Gc), 256, 0, stream>>>(
        T2, Wg2, bg2, nullptr, pp, g0);
  }
  k_pool_final<<<(NG * E3C + 255) / 256, 256, 0, stream>>>(pp, pooled);
  k_fc<<<NG, 64, 0, stream>>>(pooled, con, Wfc, bfc, xfc);
  k_build<<<27, 64, 0, stream>>>(muQ, sigQ, xfc, xA);
  for (int l = 0; l < NL; ++l) {
    k_attn<<<1, 512, 0, stream>>>(xA, xB,
        Wqkv + (size_t)l * 96 * ZZ, bqkv + l * 96,
        Wo + (size_t)l * ZZ * ZZ, bo + l * ZZ,
        l1s + l * ZZ, l1b + l * ZZ);
    k_ff<<<27 * BB, 256, 0, stream>>>(xB, xA,
        W1 + (size_t)l * FF_DIM * ZZ, b1 + l * FF_DIM,
        W2 + (size_t)l * ZZ * FF_DIM, b2 + l * ZZ,
        l2s + l * ZZ, l2b + l * ZZ);
  }
  k_out<<<(1856 + 255) / 256, 256, 0, stream>>>(xA, (float*)d_out);
}